// Round 16
// baseline (146.336 us; speedup 1.0000x reference)
//
#include <hip/hip_runtime.h>
#include <hip/hip_bf16.h>

#define DEVI static __device__ __forceinline__

typedef __attribute__((ext_vector_type(4))) float f32x4;
typedef __attribute__((ext_vector_type(8))) short bf16x8;
typedef __attribute__((ext_vector_type(4))) short s16x4;
typedef __attribute__((ext_vector_type(2))) unsigned int u32x2;

DEVI unsigned short f2bf(float f) {
    union { float f; unsigned u; } v; v.f = f;
    unsigned r = v.u + 0x7fffu + ((v.u >> 16) & 1u);
    return (unsigned short)(r >> 16);
}

DEVI void gload_lds16(const void* g, void* l) {
    __builtin_amdgcn_global_load_lds(
        (const __attribute__((address_space(1))) unsigned int*)(g),
        (__attribute__((address_space(3))) unsigned int*)(l), 16, 0, 0);
}

#define EXP2A(d, x) asm("v_exp_f32 %0, %1" : "=v"(d) : "v"(x))
#define CVTPK(d, a, b) asm("v_cvt_pk_bf16_f32 %0, %1, %2" : "=v"(d) : "v"(a), "v"(b))

// ---------------------------------------------------------------- merged prep
// + wqkvT[sel][d][c] = w_qkv[512+sel*512+c][d]  (transposed k/v weight block, bf16)
__global__ __launch_bounds__(256) void prep_kernel(
    const float* __restrict__ x, const float* __restrict__ w_qkv,
    const float* __restrict__ w_proj, const float* __restrict__ w_ke,
    const float* __restrict__ w_ve,
    unsigned short* __restrict__ xb, unsigned short* __restrict__ wqkvb,
    unsigned short* __restrict__ wprojb, unsigned short* __restrict__ w2k,
    unsigned short* __restrict__ w2v, unsigned short* __restrict__ wqkvT)
{
    const int blk = blockIdx.x, t = threadIdx.x;
    if (blk < 9216) {
        const float* src; unsigned short* dst; int i;
        if (blk < 8192)      { src = x;      dst = xb;     i = (blk * 256 + t) * 4; }
        else if (blk < 8960) { src = w_qkv;  dst = wqkvb;  i = ((blk - 8192) * 256 + t) * 4; }
        else                 { src = w_proj; dst = wprojb; i = ((blk - 8960) * 256 + t) * 4; }
        const float4 v = *(const float4*)(src + i);
        ushort4 o; o.x = f2bf(v.x); o.y = f2bf(v.y); o.z = f2bf(v.z); o.w = f2bf(v.w);
        *(ushort4*)(dst + i) = o;
    } else if (blk < 11264) {
        const int r = blk - 9216;
        const float* wsrc = (r < 1024) ? w_ke : w_ve;
        unsigned short* wdst = (r < 1024) ? w2k : w2v;
        const int i4 = (((r & 1023) * 256) + t) * 4;
        const int o = i4 >> 11, p = (i4 >> 9) & 3, c = i4 & 511;
        const float* s = wsrc + (o << 11) + (c << 2) + p;
        ushort4 ov; ov.x = f2bf(s[0]); ov.y = f2bf(s[4]); ov.z = f2bf(s[8]); ov.w = f2bf(s[12]);
        *(ushort4*)(wdst + i4) = ov;
    } else {
        // transpose k/v weight block: wqkvT[sel*262144 + d*512 + c] = w_qkv[(512+sel*512+c)*512 + d]
        const int r2 = blk - 11264;                 // 0..511
        const int i4 = (r2 * 256 + t) * 4;          // 0..2097151 step 4
        const int sel = i4 >> 18;
        const int rem = i4 & 262143;
        const int d = rem >> 9, c4 = rem & 511;
        const float* s = w_qkv + (size_t)(512 + sel * 512 + c4) * 512 + d;
        ushort4 ov; ov.x = f2bf(s[0]); ov.y = f2bf(s[512]); ov.z = f2bf(s[1024]); ov.w = f2bf(s[1536]);
        *(ushort4*)(wqkvT + i4) = ov;
    }
}

// ---------------------------------------------------------------- combined-weight GEMM (NT), strided A/C
// Wt[o][p*512+d] = sum_c w2[o][p*512+c] * wqkvT[sel][d][c]
__global__ __launch_bounds__(256) void gemm_wt(
    const unsigned short* __restrict__ w2k,
    const unsigned short* __restrict__ w2v,
    const unsigned short* __restrict__ wqkvT,
    unsigned short* __restrict__ wtk,
    unsigned short* __restrict__ wtv)
{
    __shared__ unsigned short As[128 * 64];
    __shared__ unsigned short Bs[128 * 64];
    const int t = threadIdx.x;
    const int lane = t & 63, w = t >> 6;
    const int wr = w >> 1, wc = w & 1;
    const int lr = lane & 15, lg = lane >> 4;
    const int rowBase = blockIdx.y * 128;    // o
    const int colBase = blockIdx.x * 128;    // d
    const int p = blockIdx.z & 3, sel = blockIdx.z >> 2;
    const unsigned short* A = (sel ? w2v : w2k) + p * 512;      // stride 2048
    const unsigned short* B = wqkvT + (size_t)sel * 262144;     // [d][c], stride 512
    unsigned short* C = (sel ? wtv : wtk) + p * 512;            // stride 2048

    const unsigned short* gA[4]; const unsigned short* gB[4]; int du[4];
#pragma unroll
    for (int j = 0; j < 4; ++j) {
        const int u = t * 16 + j * 4096;
        const int row = u >> 7, colb = u & 127;
        const int csw = colb ^ ((row & 7) << 4);
        du[j] = u;
        gA[j] = A + (size_t)(rowBase + row) * 2048 + (csw >> 1);
        gB[j] = B + (size_t)(colBase + row) * 512 + (csw >> 1);
    }
    const int sw = (lr & 7) << 4;

    f32x4 acc[4][4] = {};

    for (int k0 = 0; k0 < 512; k0 += 64) {
#pragma unroll
        for (int j = 0; j < 4; ++j) {
            gload_lds16(gA[j] + k0, (char*)As + du[j]);
            gload_lds16(gB[j] + k0, (char*)Bs + du[j]);
        }
        __syncthreads();
#pragma unroll
        for (int s = 0; s < 2; ++s) {
            const int ro = (s * 64 + lg * 16) ^ sw;
            bf16x8 af[4], bfr[4];
#pragma unroll
            for (int a = 0; a < 4; ++a)
                af[a] = *(const bf16x8*)((char*)As + (wr * 64 + a * 16 + lr) * 128 + ro);
#pragma unroll
            for (int bn = 0; bn < 4; ++bn)
                bfr[bn] = *(const bf16x8*)((char*)Bs + (wc * 64 + bn * 16 + lr) * 128 + ro);
#pragma unroll
            for (int a = 0; a < 4; ++a)
#pragma unroll
                for (int bn = 0; bn < 4; ++bn)
                    acc[a][bn] = __builtin_amdgcn_mfma_f32_16x16x32_bf16(af[a], bfr[bn], acc[a][bn], 0, 0, 0);
        }
        __syncthreads();
    }

#pragma unroll
    for (int a = 0; a < 4; ++a) {
        const size_t row = (size_t)rowBase + wr * 64 + a * 16 + lg * 4;
#pragma unroll
        for (int bn = 0; bn < 4; ++bn) {
            const size_t col = (size_t)colBase + wc * 64 + bn * 16 + lr;
#pragma unroll
            for (int r = 0; r < 4; ++r)
                C[(row + r) * 2048 + col] = f2bf(acc[a][bn][r]);
        }
    }
}

// ---------------------------------------------------------------- fused q-projection + k/v reduction GEMM (split-K=2)
// XCD-chunk swizzle: nid = (id%8)*128 + id/8 -> each XCD owns a contiguous 128-block
// chunk (A-panel slice ~4MB, L2-resident). grid (4, 256).
__global__ __launch_bounds__(256) void gemm_qred(
    const unsigned short* __restrict__ xb,
    const unsigned short* __restrict__ wqkvb,
    unsigned short* __restrict__ qbuf,
    const unsigned short* __restrict__ wtk,
    const unsigned short* __restrict__ wtv,
    float* __restrict__ kred)   // [2 ks][8192][512], base = kredB
{
    __shared__ unsigned short As[128 * 64];
    __shared__ unsigned short Bs[128 * 64];
    const int t = threadIdx.x;
    const int lane = t & 63, w = t >> 6;
    const int wr = w >> 1, wc = w & 1;
    const int lr = lane & 15, lg = lane >> 4;
    const int sw = (lr & 7) << 4;

    const int id = blockIdx.y * 4 + blockIdx.x;            // 0..1023
    const int nid = (id & 7) * 128 + (id >> 3);            // bijective XCD chunking
    const int bx = nid & 3, by = nid >> 2;
    const int colBase = bx * 128;

    if (by < 128) {
        // ---------------- q = xb @ wqkvb[0:512]^T  (verbatim gemm_bt<1,0> body)
        const size_t rowBase = (size_t)by * 128;
        const unsigned short* gA[4]; const unsigned short* gB[4]; int du[4];
#pragma unroll
        for (int j = 0; j < 4; ++j) {
            const int u = t * 16 + j * 4096;
            const int row = u >> 7, colb = u & 127;
            const int csw = colb ^ ((row & 7) << 4);
            du[j] = u;
            gA[j] = xb + (rowBase + row) * (size_t)512 + (csw >> 1);
            gB[j] = wqkvb + (colBase + row) * (size_t)512 + (csw >> 1);
        }
        f32x4 acc[4][4] = {};
        for (int k0 = 0; k0 < 512; k0 += 64) {
#pragma unroll
            for (int j = 0; j < 4; ++j) {
                gload_lds16(gA[j] + k0, (char*)As + du[j]);
                gload_lds16(gB[j] + k0, (char*)Bs + du[j]);
            }
            __syncthreads();
#pragma unroll
            for (int s = 0; s < 2; ++s) {
                const int ro = (s * 64 + lg * 16) ^ sw;
                bf16x8 af[4], bfr[4];
#pragma unroll
                for (int a = 0; a < 4; ++a)
                    af[a] = *(const bf16x8*)((char*)As + (wr * 64 + a * 16 + lr) * 128 + ro);
#pragma unroll
                for (int bn = 0; bn < 4; ++bn)
                    bfr[bn] = *(const bf16x8*)((char*)Bs + (wc * 64 + bn * 16 + lr) * 128 + ro);
#pragma unroll
                for (int a = 0; a < 4; ++a)
#pragma unroll
                    for (int bn = 0; bn < 4; ++bn)
                        acc[a][bn] = __builtin_amdgcn_mfma_f32_16x16x32_bf16(af[a], bfr[bn], acc[a][bn], 0, 0, 0);
            }
            __syncthreads();
        }
#pragma unroll
        for (int a = 0; a < 4; ++a) {
            const size_t row = rowBase + wr * 64 + a * 16 + lg * 4;
#pragma unroll
            for (int bn = 0; bn < 4; ++bn) {
                const size_t col = (size_t)colBase + wc * 64 + bn * 16 + lr;
#pragma unroll
                for (int r = 0; r < 4; ++r)
                    qbuf[(row + r) * 512 + col] = f2bf(acc[a][bn][r]);
            }
        }
    } else {
        // ---------------- k/v reduction on x-patches (split-K=2, verbatim R12 body)
        const int z = by - 128;
        const int ks = z >> 6;
        const int rowBase = (z & 63) * 128;
        const int isV = rowBase >= 4096;
        const unsigned short* Bp = isV ? wtv : wtk;

        const char* gA[4]; const unsigned short* gB[4]; int du[4];
#pragma unroll
        for (int j = 0; j < 4; ++j) {
            const int u = t * 16 + j * 4096;
            const int row = u >> 7, colb = u & 127;
            const int csw = colb ^ ((row & 7) << 4);
            du[j] = u;
            const int bm = (rowBase + row) & 4095;
            const int b = bm >> 10, m = bm & 1023;
            const int pix = (m >> 5) * 128 + (m & 31) * 2;
            gA[j] = (const char*)xb + (size_t)(b * 4096 + pix) * 1024 + csw;
            gB[j] = Bp + (colBase + row) * (size_t)2048 + (csw >> 1);
        }
        f32x4 acc[4][4] = {};
        for (int kk = 0; kk < 16; ++kk) {
            const int k0 = ks * 1024 + kk * 64;
            const int p = k0 >> 9;
            const int pd = ((p & 1) ? 1 : 0) + ((p & 2) ? 64 : 0);
            const size_t aoff = (size_t)pd * 1024 + (size_t)(k0 & 511) * 2;
#pragma unroll
            for (int j = 0; j < 4; ++j) {
                gload_lds16(gA[j] + aoff, (char*)As + du[j]);
                gload_lds16(gB[j] + k0, (char*)Bs + du[j]);
            }
            __syncthreads();
#pragma unroll
            for (int s = 0; s < 2; ++s) {
                const int ro = (s * 64 + lg * 16) ^ sw;
                bf16x8 af[4], bfr[4];
#pragma unroll
                for (int a = 0; a < 4; ++a)
                    af[a] = *(const bf16x8*)((char*)As + (wr * 64 + a * 16 + lr) * 128 + ro);
#pragma unroll
                for (int bn = 0; bn < 4; ++bn)
                    bfr[bn] = *(const bf16x8*)((char*)Bs + (wc * 64 + bn * 16 + lr) * 128 + ro);
#pragma unroll
                for (int a = 0; a < 4; ++a)
#pragma unroll
                    for (int bn = 0; bn < 4; ++bn)
                        acc[a][bn] = __builtin_amdgcn_mfma_f32_16x16x32_bf16(af[a], bfr[bn], acc[a][bn], 0, 0, 0);
            }
            __syncthreads();
        }
        float* outp = kred + (size_t)ks * 4194304;
#pragma unroll
        for (int a = 0; a < 4; ++a) {
            const size_t row = (size_t)rowBase + wr * 64 + a * 16 + lg * 4;
#pragma unroll
            for (int bn = 0; bn < 4; ++bn) {
                const size_t col = (size_t)colBase + wc * 64 + bn * 16 + lr;
#pragma unroll
                for (int r = 0; r < 4; ++r)
                    outp[(row + r) * 512 + col] = acc[a][bn][r];
            }
        }
    }
}

// ---------------------------------------------------------------- merged LN: k-LN (blk<4096) + fused v-LN+transpose (blk>=4096)
// k output pre-scaled by 0.125*log2(e); v normalized and written transposed to v_t.
__global__ __launch_bounds__(256) void ln_all(
    const float* __restrict__ kredA, const float* __restrict__ kredB,
    const float* __restrict__ gk, const float* __restrict__ bk,
    const float* __restrict__ gv, const float* __restrict__ bv,
    unsigned short* __restrict__ k_ln, unsigned short* __restrict__ v_t)
{
    const int blk = blockIdx.x, t = threadIdx.x;
    if (blk < 4096) {
        const size_t off = (size_t)blk * 512;
        const float QS = 0.18033688011112042f;
        unsigned short* o = k_ln + off;
        const float2 a = *(const float2*)(kredA + off + t * 2);
        const float2 b2 = *(const float2*)(kredB + off + t * 2);
        const float vx = a.x + b2.x, vy = a.y + b2.y;
        float s = vx + vy, s2 = vx * vx + vy * vy;
#pragma unroll
        for (int o2 = 1; o2 <= 16; o2 <<= 1) {
            s += __shfl_xor(s, o2);
            s2 += __shfl_xor(s2, o2);
        }
        const float mean = s * 0.015625f;
        const float var = s2 * 0.015625f - mean * mean;
        const float rstd = rsqrtf(var + 1e-5f);
        const int c = (t * 2) & 63;
        ushort2 ov;
        ov.x = f2bf(((vx - mean) * rstd * gk[c] + bk[c]) * QS);
        ov.y = f2bf(((vy - mean) * rstd * gk[c + 1] + bk[c + 1]) * QS);
        *(ushort2*)(o + t * 2) = ov;
    } else {
        __shared__ unsigned short tile[64][65];
        const int r2 = blk - 4096;          // 0..511
        const int mb = r2 >> 3, cb = r2 & 7;
        const int r = t >> 2, qt = t & 3;

        const size_t base = ((size_t)(4096 + mb * 64 + r)) * 512 + cb * 64 + qt * 16;
        float v[16];
        float s = 0.f, s2 = 0.f;
#pragma unroll
        for (int i = 0; i < 4; ++i) {
            const float4 a = *(const float4*)(kredA + base + i * 4);
            const float4 b2 = *(const float4*)(kredB + base + i * 4);
            const float e0 = a.x + b2.x, e1 = a.y + b2.y, e2 = a.z + b2.z, e3 = a.w + b2.w;
            v[i * 4 + 0] = e0; v[i * 4 + 1] = e1; v[i * 4 + 2] = e2; v[i * 4 + 3] = e3;
            s += (e0 + e1) + (e2 + e3);
            s2 += (e0 * e0 + e1 * e1) + (e2 * e2 + e3 * e3);
        }
        s += __shfl_xor(s, 1); s += __shfl_xor(s, 2);
        s2 += __shfl_xor(s2, 1); s2 += __shfl_xor(s2, 2);
        const float mean = s * 0.015625f;
        const float var = s2 * 0.015625f - mean * mean;
        const float rstd = rsqrtf(var + 1e-5f);
#pragma unroll
        for (int i = 0; i < 16; ++i) {
            const int c = qt * 16 + i;
            tile[r][c] = f2bf((v[i] - mean) * rstd * gv[c] + bv[c]);
        }
        __syncthreads();
        const int b = mb >> 4;
        const int mloc = (mb & 15) * 64;
#pragma unroll
        for (int i = 0; i < 16; ++i) {
            const int idx = i * 256 + t;
            const int c = idx >> 6, m = idx & 63;
            v_t[((size_t)(b * 512) + cb * 64 + c) * 1024 + mloc + m] = tile[m][c];
        }
    }
}

// ---------------------------------------------------------------- output projection GEMM, 64x128 tiles + XCD chunk swizzle
// out[M=16384][512] = attn_o @ wproj^T + bias, f32 out. grid (4, 256).
__global__ __launch_bounds__(256) void gemm_proj(
    const unsigned short* __restrict__ A,
    const unsigned short* __restrict__ B,
    float* __restrict__ C, const float* __restrict__ bias)
{
    __shared__ unsigned short As[64 * 64];    // 8 KB
    __shared__ unsigned short Bs[128 * 64];   // 16 KB
    const int t = threadIdx.x;
    const int lane = t & 63, w = t >> 6;
    const int wr = w >> 1, wc = w & 1;
    const int lr = lane & 15, lg = lane >> 4;
    const int id = blockIdx.y * 4 + blockIdx.x;
    const int nid = (id & 7) * 128 + (id >> 3);
    const size_t rowBase = (size_t)(nid >> 2) * 64;
    const size_t colBase = (size_t)(nid & 3) * 128;

    const unsigned short* gA[2]; const unsigned short* gB[4]; int duA[2], duB[4];
#pragma unroll
    for (int j = 0; j < 2; ++j) {
        const int u = t * 16 + j * 4096;
        const int row = u >> 7, colb = u & 127;
        const int csw = colb ^ ((row & 7) << 4);
        duA[j] = u;
        gA[j] = A + (rowBase + row) * (size_t)512 + (csw >> 1);
    }
#pragma unroll
    for (int j = 0; j < 4; ++j) {
        const int u = t * 16 + j * 4096;
        const int row = u >> 7, colb = u & 127;
        const int csw = colb ^ ((row & 7) << 4);
        duB[j] = u;
        gB[j] = B + (colBase + row) * (size_t)512 + (csw >> 1);
    }
    const int sw = (lr & 7) << 4;

    f32x4 acc[2][4] = {};

    for (int k0 = 0; k0 < 512; k0 += 64) {
#pragma unroll
        for (int j = 0; j < 2; ++j)
            gload_lds16(gA[j] + k0, (char*)As + duA[j]);
#pragma unroll
        for (int j = 0; j < 4; ++j)
            gload_lds16(gB[j] + k0, (char*)Bs + duB[j]);
        __syncthreads();
#pragma unroll
        for (int s = 0; s < 2; ++s) {
            const int ro = (s * 64 + lg * 16) ^ sw;
            bf16x8 af[2], bfr[4];
#pragma unroll
            for (int a = 0; a < 2; ++a)
                af[a] = *(const bf16x8*)((char*)As + (wr * 32 + a * 16 + lr) * 128 + ro);
#pragma unroll
            for (int bn = 0; bn < 4; ++bn)
                bfr[bn] = *(const bf16x8*)((char*)Bs + (wc * 64 + bn * 16 + lr) * 128 + ro);
#pragma unroll
            for (int a = 0; a < 2; ++a)
#pragma unroll
                for (int bn = 0; bn < 4; ++bn)
                    acc[a][bn] = __builtin_amdgcn_mfma_f32_16x16x32_bf16(af[a], bfr[bn], acc[a][bn], 0, 0, 0);
        }
        __syncthreads();
    }

#pragma unroll
    for (int a = 0; a < 2; ++a) {
        const size_t row = rowBase + wr * 32 + a * 16 + lg * 4;
#pragma unroll
        for (int bn = 0; bn < 4; ++bn) {
            const size_t col = colBase + wc * 64 + bn * 16 + lr;
#pragma unroll
            for (int r = 0; r < 4; ++r)
                C[(row + r) * 512 + col] = acc[a][bn][r] + bias[col];
        }
    }
}

// ---------------------------------------------------------------- flash attention v7 (R11-proven, no setprio)
__global__ __launch_bounds__(256) void attn_kernel(
    const unsigned short* __restrict__ qb,
    const unsigned short* __restrict__ k_ln,
    const unsigned short* __restrict__ v_t,
    unsigned short* __restrict__ attn_out)
{
    extern __shared__ char smem[];
    const int blk = ((blockIdx.x & 7) << 7) | (blockIdx.x >> 3);   // bijective XCD swizzle (1024 % 8 == 0)
    const int qc = blk & 31, h = (blk >> 5) & 7, b = blk >> 8;
    const int t = threadIdx.x, w = t >> 6, lane = t & 63;
    const int lr = lane & 15, lg = lane >> 4;
    const int qrow0 = qc * 128 + w * 32;

    const unsigned short* qpA = qb + (size_t)(b * 4096 + qrow0 + lr) * 512 + h * 64 + lg * 8;
    const bf16x8 qa0 = *(const bf16x8*)(qpA);
    const bf16x8 qa1 = *(const bf16x8*)(qpA + 32);
    const bf16x8 qb0 = *(const bf16x8*)(qpA + 16 * 512);
    const bf16x8 qb1 = *(const bf16x8*)(qpA + 16 * 512 + 32);

    const char* kbase = (const char*)(k_ln + (size_t)b * 524288 + h * 64);
    const char* vbase = (const char*)(v_t + ((size_t)b * 512 + h * 64) * 1024);
    const int d0 = t * 16, d1 = 4096 + t * 16;
    const int r0 = d0 >> 7, cs0 = (d0 & 127) ^ ((r0 & 7) << 4);
    const int r1 = d1 >> 7, cs1 = (d1 & 127) ^ ((r1 & 7) << 4);
    const char* gK0 = kbase + r0 * 1024 + cs0;
    const char* gK1 = kbase + r1 * 1024 + cs1;
    const char* gV0 = vbase + r0 * 2048 + cs0;
    const char* gV1 = vbase + r1 * 2048 + cs1;

#define STAGE_KV(buf, kt) do { \
    gload_lds16(gK0 + (size_t)(kt) * 65536, smem + (buf) * 8192 + d0); \
    gload_lds16(gK1 + (size_t)(kt) * 65536, smem + (buf) * 8192 + d1); \
    gload_lds16(gV0 + (kt) * 128, smem + 16384 + (buf) * 8192 + d0); \
    gload_lds16(gV1 + (kt) * 128, smem + 16384 + (buf) * 8192 + d1); \
  } while (0)

    bf16x8 ones;
#pragma unroll
    for (int i = 0; i < 8; ++i) ones[i] = (short)0x3F80;   // bf16 1.0

    f32x4 accA[4] = {}, accB[4] = {};
    f32x4 psaccA = {}, psaccB = {};

    STAGE_KV(0, 0);
    __syncthreads();

    char* Pw = smem + 32768 + w * 2048;
    const int sw = (lr & 7) << 4;
    const int off0 = lr * 128 + ((lg * 16) ^ sw);
    const int off1 = lr * 128 + ((64 + lg * 16) ^ sw);
    int pwo[4];
#pragma unroll
    for (int tt = 0; tt < 4; ++tt) pwo[tt] = lr * 128 + ((tt * 32 + lg * 8) ^ sw);

#pragma unroll 2
    for (int kt = 0; kt < 16; ++kt) {
        const int cur = kt & 1;
        if (kt < 15) STAGE_KV(cur ^ 1, kt + 1);
        const char* KsB = smem + cur * 8192;
        const char* VsB = smem + 16384 + cur * 8192;

        // QK^T, operand-swapped: sa[tt][r] = S[key=tt*16+lg*4+r][q=lr] (pre-scaled via k_ln)
        f32x4 sa[4], sb[4];
#pragma unroll
        for (int tt = 0; tt < 4; ++tt) {
            const bf16x8 kf0 = *(const bf16x8*)(KsB + tt * 2048 + off0);
            const bf16x8 kf1 = *(const bf16x8*)(KsB + tt * 2048 + off1);
            f32x4 za = {}, zb = {};
            za = __builtin_amdgcn_mfma_f32_16x16x32_bf16(kf0, qa0, za, 0, 0, 0);
            za = __builtin_amdgcn_mfma_f32_16x16x32_bf16(kf1, qa1, za, 0, 0, 0);
            zb = __builtin_amdgcn_mfma_f32_16x16x32_bf16(kf0, qb0, zb, 0, 0, 0);
            zb = __builtin_amdgcn_mfma_f32_16x16x32_bf16(kf1, qb1, zb, 0, 0, 0);
            sa[tt] = za; sb[tt] = zb;
        }

        // half A: p = exp2(s), pack 4 consecutive keys, swizzled b64 write
#pragma unroll
        for (int tt = 0; tt < 4; ++tt) {
            float e0, e1, e2, e3;
            EXP2A(e0, sa[tt][0]); EXP2A(e1, sa[tt][1]);
            EXP2A(e2, sa[tt][2]); EXP2A(e3, sa[tt][3]);
            unsigned c0, c1;
            CVTPK(c0, e0, e1); CVTPK(c1, e2, e3);
            union { u32x2 u; s16x4 s; } pk; pk.u.x = c0; pk.u.y = c1;
            *(s16x4*)(Pw + pwo[tt]) = pk.s;
        }
        asm volatile("" ::: "memory");   // program-order the aliasing DS write->read
        const bf16x8 fa0 = *(const bf16x8*)(Pw + off0);
        const bf16x8 fa1 = *(const bf16x8*)(Pw + off1);
        asm volatile("" ::: "memory");

        // hoist V fragments to registers (same 8 ds_read_b128, issued once)
        bf16x8 vf0[4], vf1[4];
#pragma unroll
        for (int n2 = 0; n2 < 4; ++n2) {
            vf0[n2] = *(const bf16x8*)(VsB + n2 * 2048 + off0);
            vf1[n2] = *(const bf16x8*)(VsB + n2 * 2048 + off1);
        }

        // PV-A + psacc-A (MFMA pipe) — overlaps with half-B softmax (VALU pipe) below
#pragma unroll
        for (int n2 = 0; n2 < 4; ++n2) {
            accA[n2] = __builtin_amdgcn_mfma_f32_16x16x32_bf16(fa0, vf0[n2], accA[n2], 0, 0, 0);
            accA[n2] = __builtin_amdgcn_mfma_f32_16x16x32_bf16(fa1, vf1[n2], accA[n2], 0, 0, 0);
        }
        psaccA = __builtin_amdgcn_mfma_f32_16x16x32_bf16(fa0, ones, psaccA, 0, 0, 0);
        psaccA = __builtin_amdgcn_mfma_f32_16x16x32_bf16(fa1, ones, psaccA, 0, 0, 0);

        // half B reuses Pw (same-wave DS ops execute in order)
#pragma unroll
        for (int tt = 0; tt < 4; ++tt) {
            float e0, e1, e2, e3;
            EXP2A(e0, sb[tt][0]); EXP2A(e1, sb[tt][1]);
            EXP2A(e2, sb[tt][2]); EXP2A(e3, sb[tt][3]);
            unsigned c0, c1;
            CVTPK(c0, e0, e1); CVTPK(c1, e2, e3);
            union { u32x2 u; s16x4 s; } pk; pk.u.x = c0; pk.u.y = c1;
            *(s16x4*)(Pw + pwo[tt]) = pk.s;
        }
        asm volatile("" ::: "memory");
        const bf16x8 fb0 = *(const bf16x8*)(Pw + off0);
        const bf16x8 fb1 = *(const bf16x8*)(Pw + off1);

#pragma unroll
        for (int n2 = 0; n2 < 4; ++n2) {
            accB[n2] = __builtin_amdgcn_mfma_f32_16x16x32_bf16(fb0, vf0[n2], accB[n2], 0, 0, 0);
            accB[n2] = __builtin_amdgcn_mfma_f32_16x16x32_bf16(fb1, vf1[n2], accB[n2], 0, 0, 0);
        }
        psaccB = __builtin_amdgcn_mfma_f32_16x16x32_bf16(fb0, ones, psaccB, 0, 0, 0);
        psaccB = __builtin_amdgcn_mfma_f32_16x16x32_bf16(fb1, ones, psaccB, 0, 0, 0);
        __syncthreads();
    }
#undef STAGE_KV

    // psacc[r] = sum over all keys of P[q=lg*4+r][*] — matches output row indexing exactly
    float dA[4], dB[4];
#pragma unroll
    for (int r = 0; r < 4; ++r) {
        dA[r] = 1.0f / psaccA[r];
        dB[r] = 1.0f / psaccB[r];
    }
    unsigned short* oA = attn_out + (size_t)(b * 4096 + qrow0 + lg * 4) * 512 + h * 64;
#pragma unroll
    for (int n2 = 0; n2 < 4; ++n2)
#pragma unroll
        for (int r = 0; r < 4; ++r) {
            oA[(size_t)r * 512 + n2 * 16 + lr] = f2bf(accA[n2][r] * dA[r]);
            oA[(size_t)(16 + r) * 512 + n2 * 16 + lr] = f2bf(accB[n2][r] * dB[r]);
        }
}

// ---------------------------------------------------------------- launch
extern "C" void kernel_launch(void* const* d_in, const int* in_sizes, int n_in,
                              void* d_out, int out_size, void* d_ws, size_t ws_size,
                              hipStream_t stream)
{
    (void)in_sizes; (void)n_in; (void)out_size; (void)ws_size;
    const float* x       = (const float*)d_in[0];
    const float* w_qkv   = (const float*)d_in[1];
    const float* w_ke    = (const float*)d_in[2];
    const float* w_ve    = (const float*)d_in[3];
    const float* gamma_k = (const float*)d_in[4];
    const float* beta_k  = (const float*)d_in[5];
    const float* gamma_v = (const float*)d_in[6];
    const float* beta_v  = (const float*)d_in[7];
    const float* w_proj  = (const float*)d_in[8];
    const float* b_proj  = (const float*)d_in[9];
    float* out = (float*)d_out;

    char* ws = (char*)d_ws;
    unsigned short* qb     = (unsigned short*)(ws + 0);            // 16,777,216 (q-only projection)
    unsigned short* wtk    = (unsigned short*)(ws + 16777216);     // 2,097,152 (combined k weight)
    unsigned short* wtv    = (unsigned short*)(ws + 18874368);     // 2,097,152 (combined v weight)
    unsigned short* wqkvT  = (unsigned short*)(ws + 20971520);     // 1,048,576 (transposed k/v wqkv block)
    unsigned short* xb     = (unsigned short*)(ws + 50331648);     // 16,777,216 (reused: attn_out)
    unsigned short* attn_o = xb;
    float*          kredB  = (float*)(ws + 67108864);              // 16,777,216 (split-K partial ks=0)
    float*          kredA  = (float*)(ws + 83886080);              // 16,777,216 (split-K partial ks=1)
    unsigned short* k_ln   = (unsigned short*)(ws + 100663296);    // 4,194,304
    unsigned short* v_t    = (unsigned short*)(ws + 109051904);    // 4,194,304
    unsigned short* wqkvb  = (unsigned short*)(ws + 113246208);    // 1,572,864
    unsigned short* w2k    = (unsigned short*)(ws + 114819072);    // 2,097,152
    unsigned short* w2v    = (unsigned short*)(ws + 116916224);    // 2,097,152
    unsigned short* wprojb = (unsigned short*)(ws + 119013376);    // 524,288

    prep_kernel<<<11776, 256, 0, stream>>>(x, w_qkv, w_proj, w_ke, w_ve,
                                           xb, wqkvb, wprojb, w2k, w2v, wqkvT);

    // combined weights: Wt[o][p*512+d] = sum_c w2[o][p,c] * w_qkv[512+sel*512+c][d]
    gemm_wt<<<dim3(4, 4, 8), 256, 0, stream>>>(w2k, w2v, wqkvT, wtk, wtv);

    // fused: q = x @ w_qkv[0:512]^T  AND  k/v reduction split-K=2 (partials kredB/kredA)
    gemm_qred<<<dim3(4, 256), 256, 0, stream>>>(xb, wqkvb, qb, wtk, wtv, kredB);

    // merged: k-LN (blocks 0..4095) + v-LN+transpose (blocks 4096..4607)
    ln_all<<<4608, 256, 0, stream>>>(kredA, kredB, gamma_k, beta_k, gamma_v, beta_v,
                                     k_ln, v_t);

    attn_kernel<<<1024, 256, 40960, stream>>>(qb, k_ln, v_t, attn_o);

    // out = attn_o @ w_proj^T + b_proj   [16384 x 512], K=512, f32 out, 64x128 tiles
    gemm_proj<<<dim3(4, 256), 256, 0, stream>>>(attn_o, wprojb, out, b_proj);
}

// Round 17
// 139.609 us; speedup vs baseline: 1.0482x; 1.0482x over previous
//
#include <hip/hip_runtime.h>
#include <hip/hip_bf16.h>

#define DEVI static __device__ __forceinline__

typedef __attribute__((ext_vector_type(4))) float f32x4;
typedef __attribute__((ext_vector_type(8))) short bf16x8;
typedef __attribute__((ext_vector_type(4))) short s16x4;
typedef __attribute__((ext_vector_type(2))) unsigned int u32x2;

DEVI unsigned short f2bf(float f) {
    union { float f; unsigned u; } v; v.f = f;
    unsigned r = v.u + 0x7fffu + ((v.u >> 16) & 1u);
    return (unsigned short)(r >> 16);
}

DEVI void gload_lds16(const void* g, void* l) {
    __builtin_amdgcn_global_load_lds(
        (const __attribute__((address_space(1))) unsigned int*)(g),
        (__attribute__((address_space(3))) unsigned int*)(l), 16, 0, 0);
}

#define EXP2A(d, x) asm("v_exp_f32 %0, %1" : "=v"(d) : "v"(x))
#define CVTPK(d, a, b) asm("v_cvt_pk_bf16_f32 %0, %1, %2" : "=v"(d) : "v"(a), "v"(b))

// ---------------------------------------------------------------- merged prep
// + wqkvT[sel][d][c] = w_qkv[512+sel*512+c][d]  (transposed k/v weight block, bf16)
__global__ __launch_bounds__(256) void prep_kernel(
    const float* __restrict__ x, const float* __restrict__ w_qkv,
    const float* __restrict__ w_proj, const float* __restrict__ w_ke,
    const float* __restrict__ w_ve,
    unsigned short* __restrict__ xb, unsigned short* __restrict__ wqkvb,
    unsigned short* __restrict__ wprojb, unsigned short* __restrict__ w2k,
    unsigned short* __restrict__ w2v, unsigned short* __restrict__ wqkvT)
{
    const int blk = blockIdx.x, t = threadIdx.x;
    if (blk < 9216) {
        const float* src; unsigned short* dst; int i;
        if (blk < 8192)      { src = x;      dst = xb;     i = (blk * 256 + t) * 4; }
        else if (blk < 8960) { src = w_qkv;  dst = wqkvb;  i = ((blk - 8192) * 256 + t) * 4; }
        else                 { src = w_proj; dst = wprojb; i = ((blk - 8960) * 256 + t) * 4; }
        const float4 v = *(const float4*)(src + i);
        ushort4 o; o.x = f2bf(v.x); o.y = f2bf(v.y); o.z = f2bf(v.z); o.w = f2bf(v.w);
        *(ushort4*)(dst + i) = o;
    } else if (blk < 11264) {
        const int r = blk - 9216;
        const float* wsrc = (r < 1024) ? w_ke : w_ve;
        unsigned short* wdst = (r < 1024) ? w2k : w2v;
        const int i4 = (((r & 1023) * 256) + t) * 4;
        const int o = i4 >> 11, p = (i4 >> 9) & 3, c = i4 & 511;
        const float* s = wsrc + (o << 11) + (c << 2) + p;
        ushort4 ov; ov.x = f2bf(s[0]); ov.y = f2bf(s[4]); ov.z = f2bf(s[8]); ov.w = f2bf(s[12]);
        *(ushort4*)(wdst + i4) = ov;
    } else {
        // transpose k/v weight block: wqkvT[sel*262144 + d*512 + c] = w_qkv[(512+sel*512+c)*512 + d]
        const int r2 = blk - 11264;                 // 0..511
        const int i4 = (r2 * 256 + t) * 4;          // 0..2097151 step 4
        const int sel = i4 >> 18;
        const int rem = i4 & 262143;
        const int d = rem >> 9, c4 = rem & 511;
        const float* s = w_qkv + (size_t)(512 + sel * 512 + c4) * 512 + d;
        ushort4 ov; ov.x = f2bf(s[0]); ov.y = f2bf(s[512]); ov.z = f2bf(s[1024]); ov.w = f2bf(s[1536]);
        *(ushort4*)(wqkvT + i4) = ov;
    }
}

// ---------------------------------------------------------------- combined-weight GEMM (NT), strided A/C
// Wt[o][p*512+d] = sum_c w2[o][p*512+c] * wqkvT[sel][d][c]
__global__ __launch_bounds__(256) void gemm_wt(
    const unsigned short* __restrict__ w2k,
    const unsigned short* __restrict__ w2v,
    const unsigned short* __restrict__ wqkvT,
    unsigned short* __restrict__ wtk,
    unsigned short* __restrict__ wtv)
{
    __shared__ unsigned short As[128 * 64];
    __shared__ unsigned short Bs[128 * 64];
    const int t = threadIdx.x;
    const int lane = t & 63, w = t >> 6;
    const int wr = w >> 1, wc = w & 1;
    const int lr = lane & 15, lg = lane >> 4;
    const int rowBase = blockIdx.y * 128;    // o
    const int colBase = blockIdx.x * 128;    // d
    const int p = blockIdx.z & 3, sel = blockIdx.z >> 2;
    const unsigned short* A = (sel ? w2v : w2k) + p * 512;      // stride 2048
    const unsigned short* B = wqkvT + (size_t)sel * 262144;     // [d][c], stride 512
    unsigned short* C = (sel ? wtv : wtk) + p * 512;            // stride 2048

    const unsigned short* gA[4]; const unsigned short* gB[4]; int du[4];
#pragma unroll
    for (int j = 0; j < 4; ++j) {
        const int u = t * 16 + j * 4096;
        const int row = u >> 7, colb = u & 127;
        const int csw = colb ^ ((row & 7) << 4);
        du[j] = u;
        gA[j] = A + (size_t)(rowBase + row) * 2048 + (csw >> 1);
        gB[j] = B + (size_t)(colBase + row) * 512 + (csw >> 1);
    }
    const int sw = (lr & 7) << 4;

    f32x4 acc[4][4] = {};

    for (int k0 = 0; k0 < 512; k0 += 64) {
#pragma unroll
        for (int j = 0; j < 4; ++j) {
            gload_lds16(gA[j] + k0, (char*)As + du[j]);
            gload_lds16(gB[j] + k0, (char*)Bs + du[j]);
        }
        __syncthreads();
#pragma unroll
        for (int s = 0; s < 2; ++s) {
            const int ro = (s * 64 + lg * 16) ^ sw;
            bf16x8 af[4], bfr[4];
#pragma unroll
            for (int a = 0; a < 4; ++a)
                af[a] = *(const bf16x8*)((char*)As + (wr * 64 + a * 16 + lr) * 128 + ro);
#pragma unroll
            for (int bn = 0; bn < 4; ++bn)
                bfr[bn] = *(const bf16x8*)((char*)Bs + (wc * 64 + bn * 16 + lr) * 128 + ro);
#pragma unroll
            for (int a = 0; a < 4; ++a)
#pragma unroll
                for (int bn = 0; bn < 4; ++bn)
                    acc[a][bn] = __builtin_amdgcn_mfma_f32_16x16x32_bf16(af[a], bfr[bn], acc[a][bn], 0, 0, 0);
        }
        __syncthreads();
    }

#pragma unroll
    for (int a = 0; a < 4; ++a) {
        const size_t row = (size_t)rowBase + wr * 64 + a * 16 + lg * 4;
#pragma unroll
        for (int bn = 0; bn < 4; ++bn) {
            const size_t col = (size_t)colBase + wc * 64 + bn * 16 + lr;
#pragma unroll
            for (int r = 0; r < 4; ++r)
                C[(row + r) * 2048 + col] = f2bf(acc[a][bn][r]);
        }
    }
}

// ---------------------------------------------------------------- fused q-projection + k/v reduction GEMM (split-K=2, R15-proven linear mapping)
// grid (4, 256): y<128 -> q tile; y>=128 -> red tile z=y-128, ks=z>>6, rowBase=(z&63)*128
__global__ __launch_bounds__(256) void gemm_qred(
    const unsigned short* __restrict__ xb,
    const unsigned short* __restrict__ wqkvb,
    unsigned short* __restrict__ qbuf,
    const unsigned short* __restrict__ wtk,
    const unsigned short* __restrict__ wtv,
    float* __restrict__ kred)   // [2 ks][8192][512], base = kredB
{
    __shared__ unsigned short As[128 * 64];
    __shared__ unsigned short Bs[128 * 64];
    const int t = threadIdx.x;
    const int lane = t & 63, w = t >> 6;
    const int wr = w >> 1, wc = w & 1;
    const int lr = lane & 15, lg = lane >> 4;
    const int sw = (lr & 7) << 4;
    const int colBase = blockIdx.x * 128;

    if (blockIdx.y < 128) {
        // ---------------- q = xb @ wqkvb[0:512]^T  (verbatim gemm_bt<1,0> body)
        const size_t rowBase = (size_t)blockIdx.y * 128;
        const unsigned short* gA[4]; const unsigned short* gB[4]; int du[4];
#pragma unroll
        for (int j = 0; j < 4; ++j) {
            const int u = t * 16 + j * 4096;
            const int row = u >> 7, colb = u & 127;
            const int csw = colb ^ ((row & 7) << 4);
            du[j] = u;
            gA[j] = xb + (rowBase + row) * (size_t)512 + (csw >> 1);
            gB[j] = wqkvb + (colBase + row) * (size_t)512 + (csw >> 1);
        }
        f32x4 acc[4][4] = {};
        for (int k0 = 0; k0 < 512; k0 += 64) {
#pragma unroll
            for (int j = 0; j < 4; ++j) {
                gload_lds16(gA[j] + k0, (char*)As + du[j]);
                gload_lds16(gB[j] + k0, (char*)Bs + du[j]);
            }
            __syncthreads();
#pragma unroll
            for (int s = 0; s < 2; ++s) {
                const int ro = (s * 64 + lg * 16) ^ sw;
                bf16x8 af[4], bfr[4];
#pragma unroll
                for (int a = 0; a < 4; ++a)
                    af[a] = *(const bf16x8*)((char*)As + (wr * 64 + a * 16 + lr) * 128 + ro);
#pragma unroll
                for (int bn = 0; bn < 4; ++bn)
                    bfr[bn] = *(const bf16x8*)((char*)Bs + (wc * 64 + bn * 16 + lr) * 128 + ro);
#pragma unroll
                for (int a = 0; a < 4; ++a)
#pragma unroll
                    for (int bn = 0; bn < 4; ++bn)
                        acc[a][bn] = __builtin_amdgcn_mfma_f32_16x16x32_bf16(af[a], bfr[bn], acc[a][bn], 0, 0, 0);
            }
            __syncthreads();
        }
#pragma unroll
        for (int a = 0; a < 4; ++a) {
            const size_t row = rowBase + wr * 64 + a * 16 + lg * 4;
#pragma unroll
            for (int bn = 0; bn < 4; ++bn) {
                const size_t col = (size_t)colBase + wc * 64 + bn * 16 + lr;
#pragma unroll
                for (int r = 0; r < 4; ++r)
                    qbuf[(row + r) * 512 + col] = f2bf(acc[a][bn][r]);
            }
        }
    } else {
        // ---------------- k/v reduction on x-patches (split-K=2, verbatim R12 body)
        const int z = blockIdx.y - 128;
        const int ks = z >> 6;
        const int rowBase = (z & 63) * 128;
        const int isV = rowBase >= 4096;
        const unsigned short* Bp = isV ? wtv : wtk;

        const char* gA[4]; const unsigned short* gB[4]; int du[4];
#pragma unroll
        for (int j = 0; j < 4; ++j) {
            const int u = t * 16 + j * 4096;
            const int row = u >> 7, colb = u & 127;
            const int csw = colb ^ ((row & 7) << 4);
            du[j] = u;
            const int bm = (rowBase + row) & 4095;
            const int b = bm >> 10, m = bm & 1023;
            const int pix = (m >> 5) * 128 + (m & 31) * 2;
            gA[j] = (const char*)xb + (size_t)(b * 4096 + pix) * 1024 + csw;
            gB[j] = Bp + (colBase + row) * (size_t)2048 + (csw >> 1);
        }
        f32x4 acc[4][4] = {};
        for (int kk = 0; kk < 16; ++kk) {
            const int k0 = ks * 1024 + kk * 64;
            const int p = k0 >> 9;
            const int pd = ((p & 1) ? 1 : 0) + ((p & 2) ? 64 : 0);
            const size_t aoff = (size_t)pd * 1024 + (size_t)(k0 & 511) * 2;
#pragma unroll
            for (int j = 0; j < 4; ++j) {
                gload_lds16(gA[j] + aoff, (char*)As + du[j]);
                gload_lds16(gB[j] + k0, (char*)Bs + du[j]);
            }
            __syncthreads();
#pragma unroll
            for (int s = 0; s < 2; ++s) {
                const int ro = (s * 64 + lg * 16) ^ sw;
                bf16x8 af[4], bfr[4];
#pragma unroll
                for (int a = 0; a < 4; ++a)
                    af[a] = *(const bf16x8*)((char*)As + (wr * 64 + a * 16 + lr) * 128 + ro);
#pragma unroll
                for (int bn = 0; bn < 4; ++bn)
                    bfr[bn] = *(const bf16x8*)((char*)Bs + (wc * 64 + bn * 16 + lr) * 128 + ro);
#pragma unroll
                for (int a = 0; a < 4; ++a)
#pragma unroll
                    for (int bn = 0; bn < 4; ++bn)
                        acc[a][bn] = __builtin_amdgcn_mfma_f32_16x16x32_bf16(af[a], bfr[bn], acc[a][bn], 0, 0, 0);
            }
            __syncthreads();
        }
        float* outp = kred + (size_t)ks * 4194304;
#pragma unroll
        for (int a = 0; a < 4; ++a) {
            const size_t row = (size_t)rowBase + wr * 64 + a * 16 + lg * 4;
#pragma unroll
            for (int bn = 0; bn < 4; ++bn) {
                const size_t col = (size_t)colBase + wc * 64 + bn * 16 + lr;
#pragma unroll
                for (int r = 0; r < 4; ++r)
                    outp[(row + r) * 512 + col] = acc[a][bn][r];
            }
        }
    }
}

// ---------------------------------------------------------------- merged LN: k-LN (blk<4096) + fused v-LN+transpose (blk>=4096)
// k output pre-scaled by 0.125*log2(e); v normalized and written transposed to v_t.
__global__ __launch_bounds__(256) void ln_all(
    const float* __restrict__ kredA, const float* __restrict__ kredB,
    const float* __restrict__ gk, const float* __restrict__ bk,
    const float* __restrict__ gv, const float* __restrict__ bv,
    unsigned short* __restrict__ k_ln, unsigned short* __restrict__ v_t)
{
    const int blk = blockIdx.x, t = threadIdx.x;
    if (blk < 4096) {
        const size_t off = (size_t)blk * 512;
        const float QS = 0.18033688011112042f;
        unsigned short* o = k_ln + off;
        const float2 a = *(const float2*)(kredA + off + t * 2);
        const float2 b2 = *(const float2*)(kredB + off + t * 2);
        const float vx = a.x + b2.x, vy = a.y + b2.y;
        float s = vx + vy, s2 = vx * vx + vy * vy;
#pragma unroll
        for (int o2 = 1; o2 <= 16; o2 <<= 1) {
            s += __shfl_xor(s, o2);
            s2 += __shfl_xor(s2, o2);
        }
        const float mean = s * 0.015625f;
        const float var = s2 * 0.015625f - mean * mean;
        const float rstd = rsqrtf(var + 1e-5f);
        const int c = (t * 2) & 63;
        ushort2 ov;
        ov.x = f2bf(((vx - mean) * rstd * gk[c] + bk[c]) * QS);
        ov.y = f2bf(((vy - mean) * rstd * gk[c + 1] + bk[c + 1]) * QS);
        *(ushort2*)(o + t * 2) = ov;
    } else {
        __shared__ unsigned short tile[64][65];
        const int r2 = blk - 4096;          // 0..511
        const int mb = r2 >> 3, cb = r2 & 7;
        const int r = t >> 2, qt = t & 3;

        const size_t base = ((size_t)(4096 + mb * 64 + r)) * 512 + cb * 64 + qt * 16;
        float v[16];
        float s = 0.f, s2 = 0.f;
#pragma unroll
        for (int i = 0; i < 4; ++i) {
            const float4 a = *(const float4*)(kredA + base + i * 4);
            const float4 b2 = *(const float4*)(kredB + base + i * 4);
            const float e0 = a.x + b2.x, e1 = a.y + b2.y, e2 = a.z + b2.z, e3 = a.w + b2.w;
            v[i * 4 + 0] = e0; v[i * 4 + 1] = e1; v[i * 4 + 2] = e2; v[i * 4 + 3] = e3;
            s += (e0 + e1) + (e2 + e3);
            s2 += (e0 * e0 + e1 * e1) + (e2 * e2 + e3 * e3);
        }
        s += __shfl_xor(s, 1); s += __shfl_xor(s, 2);
        s2 += __shfl_xor(s2, 1); s2 += __shfl_xor(s2, 2);
        const float mean = s * 0.015625f;
        const float var = s2 * 0.015625f - mean * mean;
        const float rstd = rsqrtf(var + 1e-5f);
#pragma unroll
        for (int i = 0; i < 16; ++i) {
            const int c = qt * 16 + i;
            tile[r][c] = f2bf((v[i] - mean) * rstd * gv[c] + bv[c]);
        }
        __syncthreads();
        const int b = mb >> 4;
        const int mloc = (mb & 15) * 64;
#pragma unroll
        for (int i = 0; i < 16; ++i) {
            const int idx = i * 256 + t;
            const int c = idx >> 6, m = idx & 63;
            v_t[((size_t)(b * 512) + cb * 64 + c) * 1024 + mloc + m] = tile[m][c];
        }
    }
}

// ---------------------------------------------------------------- output projection GEMM, 64x128 tiles (R15-proven linear mapping)
// out[M=16384][512] = attn_o @ wproj^T + bias, f32 out. grid (4, 256).
__global__ __launch_bounds__(256) void gemm_proj(
    const unsigned short* __restrict__ A,
    const unsigned short* __restrict__ B,
    float* __restrict__ C, const float* __restrict__ bias)
{
    __shared__ unsigned short As[64 * 64];    // 8 KB
    __shared__ unsigned short Bs[128 * 64];   // 16 KB
    const int t = threadIdx.x;
    const int lane = t & 63, w = t >> 6;
    const int wr = w >> 1, wc = w & 1;
    const int lr = lane & 15, lg = lane >> 4;
    const size_t rowBase = (size_t)blockIdx.y * 64;
    const size_t colBase = (size_t)blockIdx.x * 128;

    const unsigned short* gA[2]; const unsigned short* gB[4]; int duA[2], duB[4];
#pragma unroll
    for (int j = 0; j < 2; ++j) {
        const int u = t * 16 + j * 4096;
        const int row = u >> 7, colb = u & 127;
        const int csw = colb ^ ((row & 7) << 4);
        duA[j] = u;
        gA[j] = A + (rowBase + row) * (size_t)512 + (csw >> 1);
    }
#pragma unroll
    for (int j = 0; j < 4; ++j) {
        const int u = t * 16 + j * 4096;
        const int row = u >> 7, colb = u & 127;
        const int csw = colb ^ ((row & 7) << 4);
        duB[j] = u;
        gB[j] = B + (colBase + row) * (size_t)512 + (csw >> 1);
    }
    const int sw = (lr & 7) << 4;

    f32x4 acc[2][4] = {};

    for (int k0 = 0; k0 < 512; k0 += 64) {
#pragma unroll
        for (int j = 0; j < 2; ++j)
            gload_lds16(gA[j] + k0, (char*)As + duA[j]);
#pragma unroll
        for (int j = 0; j < 4; ++j)
            gload_lds16(gB[j] + k0, (char*)Bs + duB[j]);
        __syncthreads();
#pragma unroll
        for (int s = 0; s < 2; ++s) {
            const int ro = (s * 64 + lg * 16) ^ sw;
            bf16x8 af[2], bfr[4];
#pragma unroll
            for (int a = 0; a < 2; ++a)
                af[a] = *(const bf16x8*)((char*)As + (wr * 32 + a * 16 + lr) * 128 + ro);
#pragma unroll
            for (int bn = 0; bn < 4; ++bn)
                bfr[bn] = *(const bf16x8*)((char*)Bs + (wc * 64 + bn * 16 + lr) * 128 + ro);
#pragma unroll
            for (int a = 0; a < 2; ++a)
#pragma unroll
                for (int bn = 0; bn < 4; ++bn)
                    acc[a][bn] = __builtin_amdgcn_mfma_f32_16x16x32_bf16(af[a], bfr[bn], acc[a][bn], 0, 0, 0);
        }
        __syncthreads();
    }

#pragma unroll
    for (int a = 0; a < 2; ++a) {
        const size_t row = rowBase + wr * 32 + a * 16 + lg * 4;
#pragma unroll
        for (int bn = 0; bn < 4; ++bn) {
            const size_t col = colBase + wc * 64 + bn * 16 + lr;
#pragma unroll
            for (int r = 0; r < 4; ++r)
                C[(row + r) * 512 + col] = acc[a][bn][r] + bias[col];
        }
    }
}

// ---------------------------------------------------------------- flash attention v7 (R11-proven, no setprio)
__global__ __launch_bounds__(256) void attn_kernel(
    const unsigned short* __restrict__ qb,
    const unsigned short* __restrict__ k_ln,
    const unsigned short* __restrict__ v_t,
    unsigned short* __restrict__ attn_out)
{
    extern __shared__ char smem[];
    const int blk = ((blockIdx.x & 7) << 7) | (blockIdx.x >> 3);   // bijective XCD swizzle (1024 % 8 == 0)
    const int qc = blk & 31, h = (blk >> 5) & 7, b = blk >> 8;
    const int t = threadIdx.x, w = t >> 6, lane = t & 63;
    const int lr = lane & 15, lg = lane >> 4;
    const int qrow0 = qc * 128 + w * 32;

    const unsigned short* qpA = qb + (size_t)(b * 4096 + qrow0 + lr) * 512 + h * 64 + lg * 8;
    const bf16x8 qa0 = *(const bf16x8*)(qpA);
    const bf16x8 qa1 = *(const bf16x8*)(qpA + 32);
    const bf16x8 qb0 = *(const bf16x8*)(qpA + 16 * 512);
    const bf16x8 qb1 = *(const bf16x8*)(qpA + 16 * 512 + 32);

    const char* kbase = (const char*)(k_ln + (size_t)b * 524288 + h * 64);
    const char* vbase = (const char*)(v_t + ((size_t)b * 512 + h * 64) * 1024);
    const int d0 = t * 16, d1 = 4096 + t * 16;
    const int r0 = d0 >> 7, cs0 = (d0 & 127) ^ ((r0 & 7) << 4);
    const int r1 = d1 >> 7, cs1 = (d1 & 127) ^ ((r1 & 7) << 4);
    const char* gK0 = kbase + r0 * 1024 + cs0;
    const char* gK1 = kbase + r1 * 1024 + cs1;
    const char* gV0 = vbase + r0 * 2048 + cs0;
    const char* gV1 = vbase + r1 * 2048 + cs1;

#define STAGE_KV(buf, kt) do { \
    gload_lds16(gK0 + (size_t)(kt) * 65536, smem + (buf) * 8192 + d0); \
    gload_lds16(gK1 + (size_t)(kt) * 65536, smem + (buf) * 8192 + d1); \
    gload_lds16(gV0 + (kt) * 128, smem + 16384 + (buf) * 8192 + d0); \
    gload_lds16(gV1 + (kt) * 128, smem + 16384 + (buf) * 8192 + d1); \
  } while (0)

    bf16x8 ones;
#pragma unroll
    for (int i = 0; i < 8; ++i) ones[i] = (short)0x3F80;   // bf16 1.0

    f32x4 accA[4] = {}, accB[4] = {};
    f32x4 psaccA = {}, psaccB = {};

    STAGE_KV(0, 0);
    __syncthreads();

    char* Pw = smem + 32768 + w * 2048;
    const int sw = (lr & 7) << 4;
    const int off0 = lr * 128 + ((lg * 16) ^ sw);
    const int off1 = lr * 128 + ((64 + lg * 16) ^ sw);
    int pwo[4];
#pragma unroll
    for (int tt = 0; tt < 4; ++tt) pwo[tt] = lr * 128 + ((tt * 32 + lg * 8) ^ sw);

#pragma unroll 2
    for (int kt = 0; kt < 16; ++kt) {
        const int cur = kt & 1;
        if (kt < 15) STAGE_KV(cur ^ 1, kt + 1);
        const char* KsB = smem + cur * 8192;
        const char* VsB = smem + 16384 + cur * 8192;

        // QK^T, operand-swapped: sa[tt][r] = S[key=tt*16+lg*4+r][q=lr] (pre-scaled via k_ln)
        f32x4 sa[4], sb[4];
#pragma unroll
        for (int tt = 0; tt < 4; ++tt) {
            const bf16x8 kf0 = *(const bf16x8*)(KsB + tt * 2048 + off0);
            const bf16x8 kf1 = *(const bf16x8*)(KsB + tt * 2048 + off1);
            f32x4 za = {}, zb = {};
            za = __builtin_amdgcn_mfma_f32_16x16x32_bf16(kf0, qa0, za, 0, 0, 0);
            za = __builtin_amdgcn_mfma_f32_16x16x32_bf16(kf1, qa1, za, 0, 0, 0);
            zb = __builtin_amdgcn_mfma_f32_16x16x32_bf16(kf0, qb0, zb, 0, 0, 0);
            zb = __builtin_amdgcn_mfma_f32_16x16x32_bf16(kf1, qb1, zb, 0, 0, 0);
            sa[tt] = za; sb[tt] = zb;
        }

        // half A: p = exp2(s), pack 4 consecutive keys, swizzled b64 write
#pragma unroll
        for (int tt = 0; tt < 4; ++tt) {
            float e0, e1, e2, e3;
            EXP2A(e0, sa[tt][0]); EXP2A(e1, sa[tt][1]);
            EXP2A(e2, sa[tt][2]); EXP2A(e3, sa[tt][3]);
            unsigned c0, c1;
            CVTPK(c0, e0, e1); CVTPK(c1, e2, e3);
            union { u32x2 u; s16x4 s; } pk; pk.u.x = c0; pk.u.y = c1;
            *(s16x4*)(Pw + pwo[tt]) = pk.s;
        }
        asm volatile("" ::: "memory");   // program-order the aliasing DS write->read
        const bf16x8 fa0 = *(const bf16x8*)(Pw + off0);
        const bf16x8 fa1 = *(const bf16x8*)(Pw + off1);
        asm volatile("" ::: "memory");

        // hoist V fragments to registers (same 8 ds_read_b128, issued once)
        bf16x8 vf0[4], vf1[4];
#pragma unroll
        for (int n2 = 0; n2 < 4; ++n2) {
            vf0[n2] = *(const bf16x8*)(VsB + n2 * 2048 + off0);
            vf1[n2] = *(const bf16x8*)(VsB + n2 * 2048 + off1);
        }

        // PV-A + psacc-A (MFMA pipe) — overlaps with half-B softmax (VALU pipe) below
#pragma unroll
        for (int n2 = 0; n2 < 4; ++n2) {
            accA[n2] = __builtin_amdgcn_mfma_f32_16x16x32_bf16(fa0, vf0[n2], accA[n2], 0, 0, 0);
            accA[n2] = __builtin_amdgcn_mfma_f32_16x16x32_bf16(fa1, vf1[n2], accA[n2], 0, 0, 0);
        }
        psaccA = __builtin_amdgcn_mfma_f32_16x16x32_bf16(fa0, ones, psaccA, 0, 0, 0);
        psaccA = __builtin_amdgcn_mfma_f32_16x16x32_bf16(fa1, ones, psaccA, 0, 0, 0);

        // half B reuses Pw (same-wave DS ops execute in order)
#pragma unroll
        for (int tt = 0; tt < 4; ++tt) {
            float e0, e1, e2, e3;
            EXP2A(e0, sb[tt][0]); EXP2A(e1, sb[tt][1]);
            EXP2A(e2, sb[tt][2]); EXP2A(e3, sb[tt][3]);
            unsigned c0, c1;
            CVTPK(c0, e0, e1); CVTPK(c1, e2, e3);
            union { u32x2 u; s16x4 s; } pk; pk.u.x = c0; pk.u.y = c1;
            *(s16x4*)(Pw + pwo[tt]) = pk.s;
        }
        asm volatile("" ::: "memory");
        const bf16x8 fb0 = *(const bf16x8*)(Pw + off0);
        const bf16x8 fb1 = *(const bf16x8*)(Pw + off1);

#pragma unroll
        for (int n2 = 0; n2 < 4; ++n2) {
            accB[n2] = __builtin_amdgcn_mfma_f32_16x16x32_bf16(fb0, vf0[n2], accB[n2], 0, 0, 0);
            accB[n2] = __builtin_amdgcn_mfma_f32_16x16x32_bf16(fb1, vf1[n2], accB[n2], 0, 0, 0);
        }
        psaccB = __builtin_amdgcn_mfma_f32_16x16x32_bf16(fb0, ones, psaccB, 0, 0, 0);
        psaccB = __builtin_amdgcn_mfma_f32_16x16x32_bf16(fb1, ones, psaccB, 0, 0, 0);
        __syncthreads();
    }
#undef STAGE_KV

    // psacc[r] = sum over all keys of P[q=lg*4+r][*] — matches output row indexing exactly
    float dA[4], dB[4];
#pragma unroll
    for (int r = 0; r < 4; ++r) {
        dA[r] = 1.0f / psaccA[r];
        dB[r] = 1.0f / psaccB[r];
    }
    unsigned short* oA = attn_out + (size_t)(b * 4096 + qrow0 + lg * 4) * 512 + h * 64;
#pragma unroll
    for (int n2 = 0; n2 < 4; ++n2)
#pragma unroll
        for (int r = 0; r < 4; ++r) {
            oA[(size_t)r * 512 + n2 * 16 + lr] = f2bf(accA[n2][r] * dA[r]);
            oA[(size_t)(16 + r) * 512 + n2 * 16 + lr] = f2bf(accB[n2][r] * dB[r]);
        }
}

// ---------------------------------------------------------------- launch
extern "C" void kernel_launch(void* const* d_in, const int* in_sizes, int n_in,
                              void* d_out, int out_size, void* d_ws, size_t ws_size,
                              hipStream_t stream)
{
    (void)in_sizes; (void)n_in; (void)out_size; (void)ws_size;
    const float* x       = (const float*)d_in[0];
    const float* w_qkv   = (const float*)d_in[1];
    const float* w_ke    = (const float*)d_in[2];
    const float* w_ve    = (const float*)d_in[3];
    const float* gamma_k = (const float*)d_in[4];
    const float* beta_k  = (const float*)d_in[5];
    const float* gamma_v = (const float*)d_in[6];
    const float* beta_v  = (const float*)d_in[7];
    const float* w_proj  = (const float*)d_in[8];
    const float* b_proj  = (const float*)d_in[9];
    float* out = (float*)d_out;

    char* ws = (char*)d_ws;
    unsigned short* qb     = (unsigned short*)(ws + 0);            // 16,777,216 (q-only projection)
    unsigned short* wtk    = (unsigned short*)(ws + 16777216);     // 2,097,152 (combined k weight)
    unsigned short* wtv    = (unsigned short*)(ws + 18874368);     // 2,097,152 (combined v weight)
    unsigned short* wqkvT  = (unsigned short*)(ws + 20971520);     // 1,048,576 (transposed k/v wqkv block)
    unsigned short* xb     = (unsigned short*)(ws + 50331648);     // 16,777,216 (reused: attn_out)
    unsigned short* attn_o = xb;
    float*          kredB  = (float*)(ws + 67108864);              // 16,777,216 (split-K partial ks=0)
    float*          kredA  = (float*)(ws + 83886080);              // 16,777,216 (split-K partial ks=1)
    unsigned short* k_ln   = (unsigned short*)(ws + 100663296);    // 4,194,304
    unsigned short* v_t    = (unsigned short*)(ws + 109051904);    // 4,194,304
    unsigned short* wqkvb  = (unsigned short*)(ws + 113246208);    // 1,572,864
    unsigned short* w2k    = (unsigned short*)(ws + 114819072);    // 2,097,152
    unsigned short* w2v    = (unsigned short*)(ws + 116916224);    // 2,097,152
    unsigned short* wprojb = (unsigned short*)(ws + 119013376);    // 524,288

    prep_kernel<<<11776, 256, 0, stream>>>(x, w_qkv, w_proj, w_ke, w_ve,
                                           xb, wqkvb, wprojb, w2k, w2v, wqkvT);

    // combined weights: Wt[o][p*512+d] = sum_c w2[o][p,c] * w_qkv[512+sel*512+c][d]
    gemm_wt<<<dim3(4, 4, 8), 256, 0, stream>>>(w2k, w2v, wqkvT, wtk, wtv);

    // fused: q = x @ w_qkv[0:512]^T  AND  k/v reduction split-K=2 (partials kredB/kredA)
    gemm_qred<<<dim3(4, 256), 256, 0, stream>>>(xb, wqkvb, qb, wtk, wtv, kredB);

    // merged: k-LN (blocks 0..4095) + v-LN+transpose (blocks 4096..4607)
    ln_all<<<4608, 256, 0, stream>>>(kredA, kredB, gamma_k, beta_k, gamma_v, beta_v,
                                     k_ln, v_t);

    attn_kernel<<<1024, 256, 40960, stream>>>(qb, k_ln, v_t, attn_o);

    // out = attn_o @ w_proj^T + b_proj   [16384 x 512], K=512, f32 out, 64x128 tiles
    gemm_proj<<<dim3(4, 256), 256, 0, stream>>>(attn_o, wprojb, out, b_proj);
}

// Round 19
// 139.364 us; speedup vs baseline: 1.0500x; 1.0018x over previous
//
#include <hip/hip_runtime.h>
#include <hip/hip_bf16.h>

#define DEVI static __device__ __forceinline__

typedef __attribute__((ext_vector_type(4))) float f32x4;
typedef __attribute__((ext_vector_type(8))) short bf16x8;
typedef __attribute__((ext_vector_type(4))) short s16x4;
typedef __attribute__((ext_vector_type(2))) unsigned int u32x2;

DEVI unsigned short f2bf(float f) {
    union { float f; unsigned u; } v; v.f = f;
    unsigned r = v.u + 0x7fffu + ((v.u >> 16) & 1u);
    return (unsigned short)(r >> 16);
}

DEVI void gload_lds16(const void* g, void* l) {
    __builtin_amdgcn_global_load_lds(
        (const __attribute__((address_space(1))) unsigned int*)(g),
        (__attribute__((address_space(3))) unsigned int*)(l), 16, 0, 0);
}

#define EXP2A(d, x) asm("v_exp_f32 %0, %1" : "=v"(d) : "v"(x))
#define CVTPK(d, a, b) asm("v_cvt_pk_bf16_f32 %0, %1, %2" : "=v"(d) : "v"(a), "v"(b))

// ---------------------------------------------------------------- merged prep
// + wqkvT[sel][d][c] = w_qkv[512+sel*512+c][d]  (transposed k/v weight block, bf16)
__global__ __launch_bounds__(256) void prep_kernel(
    const float* __restrict__ x, const float* __restrict__ w_qkv,
    const float* __restrict__ w_proj, const float* __restrict__ w_ke,
    const float* __restrict__ w_ve,
    unsigned short* __restrict__ xb, unsigned short* __restrict__ wqkvb,
    unsigned short* __restrict__ wprojb, unsigned short* __restrict__ w2k,
    unsigned short* __restrict__ w2v, unsigned short* __restrict__ wqkvT)
{
    const int blk = blockIdx.x, t = threadIdx.x;
    if (blk < 9216) {
        const float* src; unsigned short* dst; int i;
        if (blk < 8192)      { src = x;      dst = xb;     i = (blk * 256 + t) * 4; }
        else if (blk < 8960) { src = w_qkv;  dst = wqkvb;  i = ((blk - 8192) * 256 + t) * 4; }
        else                 { src = w_proj; dst = wprojb; i = ((blk - 8960) * 256 + t) * 4; }
        const float4 v = *(const float4*)(src + i);
        ushort4 o; o.x = f2bf(v.x); o.y = f2bf(v.y); o.z = f2bf(v.z); o.w = f2bf(v.w);
        *(ushort4*)(dst + i) = o;
    } else if (blk < 11264) {
        const int r = blk - 9216;
        const float* wsrc = (r < 1024) ? w_ke : w_ve;
        unsigned short* wdst = (r < 1024) ? w2k : w2v;
        const int i4 = (((r & 1023) * 256) + t) * 4;
        const int o = i4 >> 11, p = (i4 >> 9) & 3, c = i4 & 511;
        const float* s = wsrc + (o << 11) + (c << 2) + p;
        ushort4 ov; ov.x = f2bf(s[0]); ov.y = f2bf(s[4]); ov.z = f2bf(s[8]); ov.w = f2bf(s[12]);
        *(ushort4*)(wdst + i4) = ov;
    } else {
        // transpose k/v weight block: wqkvT[sel*262144 + d*512 + c] = w_qkv[(512+sel*512+c)*512 + d]
        const int r2 = blk - 11264;                 // 0..511
        const int i4 = (r2 * 256 + t) * 4;          // 0..2097151 step 4
        const int sel = i4 >> 18;
        const int rem = i4 & 262143;
        const int d = rem >> 9, c4 = rem & 511;
        const float* s = w_qkv + (size_t)(512 + sel * 512 + c4) * 512 + d;
        ushort4 ov; ov.x = f2bf(s[0]); ov.y = f2bf(s[512]); ov.z = f2bf(s[1024]); ov.w = f2bf(s[1536]);
        *(ushort4*)(wqkvT + i4) = ov;
    }
}

// ---------------------------------------------------------------- combined-weight GEMM (NT), strided A/C
// Wt[o][p*512+d] = sum_c w2[o][p*512+c] * wqkvT[sel][d][c]
__global__ __launch_bounds__(256) void gemm_wt(
    const unsigned short* __restrict__ w2k,
    const unsigned short* __restrict__ w2v,
    const unsigned short* __restrict__ wqkvT,
    unsigned short* __restrict__ wtk,
    unsigned short* __restrict__ wtv)
{
    __shared__ unsigned short As[128 * 64];
    __shared__ unsigned short Bs[128 * 64];
    const int t = threadIdx.x;
    const int lane = t & 63, w = t >> 6;
    const int wr = w >> 1, wc = w & 1;
    const int lr = lane & 15, lg = lane >> 4;
    const int rowBase = blockIdx.y * 128;    // o
    const int colBase = blockIdx.x * 128;    // d
    const int p = blockIdx.z & 3, sel = blockIdx.z >> 2;
    const unsigned short* A = (sel ? w2v : w2k) + p * 512;      // stride 2048
    const unsigned short* B = wqkvT + (size_t)sel * 262144;     // [d][c], stride 512
    unsigned short* C = (sel ? wtv : wtk) + p * 512;            // stride 2048

    const unsigned short* gA[4]; const unsigned short* gB[4]; int du[4];
#pragma unroll
    for (int j = 0; j < 4; ++j) {
        const int u = t * 16 + j * 4096;
        const int row = u >> 7, colb = u & 127;
        const int csw = colb ^ ((row & 7) << 4);
        du[j] = u;
        gA[j] = A + (size_t)(rowBase + row) * 2048 + (csw >> 1);
        gB[j] = B + (size_t)(colBase + row) * 512 + (csw >> 1);
    }
    const int sw = (lr & 7) << 4;

    f32x4 acc[4][4] = {};

    for (int k0 = 0; k0 < 512; k0 += 64) {
#pragma unroll
        for (int j = 0; j < 4; ++j) {
            gload_lds16(gA[j] + k0, (char*)As + du[j]);
            gload_lds16(gB[j] + k0, (char*)Bs + du[j]);
        }
        __syncthreads();
#pragma unroll
        for (int s = 0; s < 2; ++s) {
            const int ro = (s * 64 + lg * 16) ^ sw;
            bf16x8 af[4], bfr[4];
#pragma unroll
            for (int a = 0; a < 4; ++a)
                af[a] = *(const bf16x8*)((char*)As + (wr * 64 + a * 16 + lr) * 128 + ro);
#pragma unroll
            for (int bn = 0; bn < 4; ++bn)
                bfr[bn] = *(const bf16x8*)((char*)Bs + (wc * 64 + bn * 16 + lr) * 128 + ro);
#pragma unroll
            for (int a = 0; a < 4; ++a)
#pragma unroll
                for (int bn = 0; bn < 4; ++bn)
                    acc[a][bn] = __builtin_amdgcn_mfma_f32_16x16x32_bf16(af[a], bfr[bn], acc[a][bn], 0, 0, 0);
        }
        __syncthreads();
    }

#pragma unroll
    for (int a = 0; a < 4; ++a) {
        const size_t row = (size_t)rowBase + wr * 64 + a * 16 + lg * 4;
#pragma unroll
        for (int bn = 0; bn < 4; ++bn) {
            const size_t col = (size_t)colBase + wc * 64 + bn * 16 + lr;
#pragma unroll
            for (int r = 0; r < 4; ++r)
                C[(row + r) * 2048 + col] = f2bf(acc[a][bn][r]);
        }
    }
}

// ---------------------------------------------------------------- fused q-projection + k/v reduction GEMM (split-K=2, R15-proven linear mapping)
// grid (4, 256): y<128 -> q tile; y>=128 -> red tile z=y-128, ks=z>>6, rowBase=(z&63)*128
__global__ __launch_bounds__(256) void gemm_qred(
    const unsigned short* __restrict__ xb,
    const unsigned short* __restrict__ wqkvb,
    unsigned short* __restrict__ qbuf,
    const unsigned short* __restrict__ wtk,
    const unsigned short* __restrict__ wtv,
    float* __restrict__ kred)   // [2 ks][8192][512], base = kredB
{
    __shared__ unsigned short As[128 * 64];
    __shared__ unsigned short Bs[128 * 64];
    const int t = threadIdx.x;
    const int lane = t & 63, w = t >> 6;
    const int wr = w >> 1, wc = w & 1;
    const int lr = lane & 15, lg = lane >> 4;
    const int sw = (lr & 7) << 4;
    const int colBase = blockIdx.x * 128;

    if (blockIdx.y < 128) {
        // ---------------- q = xb @ wqkvb[0:512]^T  (verbatim gemm_bt<1,0> body)
        const size_t rowBase = (size_t)blockIdx.y * 128;
        const unsigned short* gA[4]; const unsigned short* gB[4]; int du[4];
#pragma unroll
        for (int j = 0; j < 4; ++j) {
            const int u = t * 16 + j * 4096;
            const int row = u >> 7, colb = u & 127;
            const int csw = colb ^ ((row & 7) << 4);
            du[j] = u;
            gA[j] = xb + (rowBase + row) * (size_t)512 + (csw >> 1);
            gB[j] = wqkvb + (colBase + row) * (size_t)512 + (csw >> 1);
        }
        f32x4 acc[4][4] = {};
        for (int k0 = 0; k0 < 512; k0 += 64) {
#pragma unroll
            for (int j = 0; j < 4; ++j) {
                gload_lds16(gA[j] + k0, (char*)As + du[j]);
                gload_lds16(gB[j] + k0, (char*)Bs + du[j]);
            }
            __syncthreads();
#pragma unroll
            for (int s = 0; s < 2; ++s) {
                const int ro = (s * 64 + lg * 16) ^ sw;
                bf16x8 af[4], bfr[4];
#pragma unroll
                for (int a = 0; a < 4; ++a)
                    af[a] = *(const bf16x8*)((char*)As + (wr * 64 + a * 16 + lr) * 128 + ro);
#pragma unroll
                for (int bn = 0; bn < 4; ++bn)
                    bfr[bn] = *(const bf16x8*)((char*)Bs + (wc * 64 + bn * 16 + lr) * 128 + ro);
#pragma unroll
                for (int a = 0; a < 4; ++a)
#pragma unroll
                    for (int bn = 0; bn < 4; ++bn)
                        acc[a][bn] = __builtin_amdgcn_mfma_f32_16x16x32_bf16(af[a], bfr[bn], acc[a][bn], 0, 0, 0);
            }
            __syncthreads();
        }
#pragma unroll
        for (int a = 0; a < 4; ++a) {
            const size_t row = rowBase + wr * 64 + a * 16 + lg * 4;
#pragma unroll
            for (int bn = 0; bn < 4; ++bn) {
                const size_t col = (size_t)colBase + wc * 64 + bn * 16 + lr;
#pragma unroll
                for (int r = 0; r < 4; ++r)
                    qbuf[(row + r) * 512 + col] = f2bf(acc[a][bn][r]);
            }
        }
    } else {
        // ---------------- k/v reduction on x-patches (split-K=2, verbatim R12 body)
        const int z = blockIdx.y - 128;
        const int ks = z >> 6;
        const int rowBase = (z & 63) * 128;
        const int isV = rowBase >= 4096;
        const unsigned short* Bp = isV ? wtv : wtk;

        const char* gA[4]; const unsigned short* gB[4]; int du[4];
#pragma unroll
        for (int j = 0; j < 4; ++j) {
            const int u = t * 16 + j * 4096;
            const int row = u >> 7, colb = u & 127;
            const int csw = colb ^ ((row & 7) << 4);
            du[j] = u;
            const int bm = (rowBase + row) & 4095;
            const int b = bm >> 10, m = bm & 1023;
            const int pix = (m >> 5) * 128 + (m & 31) * 2;
            gA[j] = (const char*)xb + (size_t)(b * 4096 + pix) * 1024 + csw;
            gB[j] = Bp + (colBase + row) * (size_t)2048 + (csw >> 1);
        }
        f32x4 acc[4][4] = {};
        for (int kk = 0; kk < 16; ++kk) {
            const int k0 = ks * 1024 + kk * 64;
            const int p = k0 >> 9;
            const int pd = ((p & 1) ? 1 : 0) + ((p & 2) ? 64 : 0);
            const size_t aoff = (size_t)pd * 1024 + (size_t)(k0 & 511) * 2;
#pragma unroll
            for (int j = 0; j < 4; ++j) {
                gload_lds16(gA[j] + aoff, (char*)As + du[j]);
                gload_lds16(gB[j] + k0, (char*)Bs + du[j]);
            }
            __syncthreads();
#pragma unroll
            for (int s = 0; s < 2; ++s) {
                const int ro = (s * 64 + lg * 16) ^ sw;
                bf16x8 af[4], bfr[4];
#pragma unroll
                for (int a = 0; a < 4; ++a)
                    af[a] = *(const bf16x8*)((char*)As + (wr * 64 + a * 16 + lr) * 128 + ro);
#pragma unroll
                for (int bn = 0; bn < 4; ++bn)
                    bfr[bn] = *(const bf16x8*)((char*)Bs + (wc * 64 + bn * 16 + lr) * 128 + ro);
#pragma unroll
                for (int a = 0; a < 4; ++a)
#pragma unroll
                    for (int bn = 0; bn < 4; ++bn)
                        acc[a][bn] = __builtin_amdgcn_mfma_f32_16x16x32_bf16(af[a], bfr[bn], acc[a][bn], 0, 0, 0);
            }
            __syncthreads();
        }
        float* outp = kred + (size_t)ks * 4194304;
#pragma unroll
        for (int a = 0; a < 4; ++a) {
            const size_t row = (size_t)rowBase + wr * 64 + a * 16 + lg * 4;
#pragma unroll
            for (int bn = 0; bn < 4; ++bn) {
                const size_t col = (size_t)colBase + wc * 64 + bn * 16 + lr;
#pragma unroll
                for (int r = 0; r < 4; ++r)
                    outp[(row + r) * 512 + col] = acc[a][bn][r];
            }
        }
    }
}

// ---------------------------------------------------------------- merged LN: k-LN (blk<4096) + fused v-LN+transpose (blk>=4096)
// k output pre-scaled by 0.125*log2(e); v normalized and written transposed to v_t.
__global__ __launch_bounds__(256) void ln_all(
    const float* __restrict__ kredA, const float* __restrict__ kredB,
    const float* __restrict__ gk, const float* __restrict__ bk,
    const float* __restrict__ gv, const float* __restrict__ bv,
    unsigned short* __restrict__ k_ln, unsigned short* __restrict__ v_t)
{
    const int blk = blockIdx.x, t = threadIdx.x;
    if (blk < 4096) {
        const size_t off = (size_t)blk * 512;
        const float QS = 0.18033688011112042f;
        unsigned short* o = k_ln + off;
        const float2 a = *(const float2*)(kredA + off + t * 2);
        const float2 b2 = *(const float2*)(kredB + off + t * 2);
        const float vx = a.x + b2.x, vy = a.y + b2.y;
        float s = vx + vy, s2 = vx * vx + vy * vy;
#pragma unroll
        for (int o2 = 1; o2 <= 16; o2 <<= 1) {
            s += __shfl_xor(s, o2);
            s2 += __shfl_xor(s2, o2);
        }
        const float mean = s * 0.015625f;
        const float var = s2 * 0.015625f - mean * mean;
        const float rstd = rsqrtf(var + 1e-5f);
        const int c = (t * 2) & 63;
        ushort2 ov;
        ov.x = f2bf(((vx - mean) * rstd * gk[c] + bk[c]) * QS);
        ov.y = f2bf(((vy - mean) * rstd * gk[c + 1] + bk[c + 1]) * QS);
        *(ushort2*)(o + t * 2) = ov;
    } else {
        __shared__ unsigned short tile[64][65];
        const int r2 = blk - 4096;          // 0..511
        const int mb = r2 >> 3, cb = r2 & 7;
        const int r = t >> 2, qt = t & 3;

        const size_t base = ((size_t)(4096 + mb * 64 + r)) * 512 + cb * 64 + qt * 16;
        float v[16];
        float s = 0.f, s2 = 0.f;
#pragma unroll
        for (int i = 0; i < 4; ++i) {
            const float4 a = *(const float4*)(kredA + base + i * 4);
            const float4 b2 = *(const float4*)(kredB + base + i * 4);
            const float e0 = a.x + b2.x, e1 = a.y + b2.y, e2 = a.z + b2.z, e3 = a.w + b2.w;
            v[i * 4 + 0] = e0; v[i * 4 + 1] = e1; v[i * 4 + 2] = e2; v[i * 4 + 3] = e3;
            s += (e0 + e1) + (e2 + e3);
            s2 += (e0 * e0 + e1 * e1) + (e2 * e2 + e3 * e3);
        }
        s += __shfl_xor(s, 1); s += __shfl_xor(s, 2);
        s2 += __shfl_xor(s2, 1); s2 += __shfl_xor(s2, 2);
        const float mean = s * 0.015625f;
        const float var = s2 * 0.015625f - mean * mean;
        const float rstd = rsqrtf(var + 1e-5f);
#pragma unroll
        for (int i = 0; i < 16; ++i) {
            const int c = qt * 16 + i;
            tile[r][c] = f2bf((v[i] - mean) * rstd * gv[c] + bv[c]);
        }
        __syncthreads();
        const int b = mb >> 4;
        const int mloc = (mb & 15) * 64;
#pragma unroll
        for (int i = 0; i < 16; ++i) {
            const int idx = i * 256 + t;
            const int c = idx >> 6, m = idx & 63;
            v_t[((size_t)(b * 512) + cb * 64 + c) * 1024 + mloc + m] = tile[m][c];
        }
    }
}

// ---------------------------------------------------------------- output projection GEMM, 64x128 tiles (R15-proven linear mapping)
// out[M=16384][512] = attn_o @ wproj^T + bias, f32 out. grid (4, 256).
__global__ __launch_bounds__(256) void gemm_proj(
    const unsigned short* __restrict__ A,
    const unsigned short* __restrict__ B,
    float* __restrict__ C, const float* __restrict__ bias)
{
    __shared__ unsigned short As[64 * 64];    // 8 KB
    __shared__ unsigned short Bs[128 * 64];   // 16 KB
    const int t = threadIdx.x;
    const int lane = t & 63, w = t >> 6;
    const int wr = w >> 1, wc = w & 1;
    const int lr = lane & 15, lg = lane >> 4;
    const size_t rowBase = (size_t)blockIdx.y * 64;
    const size_t colBase = (size_t)blockIdx.x * 128;

    const unsigned short* gA[2]; const unsigned short* gB[4]; int duA[2], duB[4];
#pragma unroll
    for (int j = 0; j < 2; ++j) {
        const int u = t * 16 + j * 4096;
        const int row = u >> 7, colb = u & 127;
        const int csw = colb ^ ((row & 7) << 4);
        duA[j] = u;
        gA[j] = A + (rowBase + row) * (size_t)512 + (csw >> 1);
    }
#pragma unroll
    for (int j = 0; j < 4; ++j) {
        const int u = t * 16 + j * 4096;
        const int row = u >> 7, colb = u & 127;
        const int csw = colb ^ ((row & 7) << 4);
        duB[j] = u;
        gB[j] = B + (colBase + row) * (size_t)512 + (csw >> 1);
    }
    const int sw = (lr & 7) << 4;

    f32x4 acc[2][4] = {};

    for (int k0 = 0; k0 < 512; k0 += 64) {
#pragma unroll
        for (int j = 0; j < 2; ++j)
            gload_lds16(gA[j] + k0, (char*)As + duA[j]);
#pragma unroll
        for (int j = 0; j < 4; ++j)
            gload_lds16(gB[j] + k0, (char*)Bs + duB[j]);
        __syncthreads();
#pragma unroll
        for (int s = 0; s < 2; ++s) {
            const int ro = (s * 64 + lg * 16) ^ sw;
            bf16x8 af[2], bfr[4];
#pragma unroll
            for (int a = 0; a < 2; ++a)
                af[a] = *(const bf16x8*)((char*)As + (wr * 32 + a * 16 + lr) * 128 + ro);
#pragma unroll
            for (int bn = 0; bn < 4; ++bn)
                bfr[bn] = *(const bf16x8*)((char*)Bs + (wc * 64 + bn * 16 + lr) * 128 + ro);
#pragma unroll
            for (int a = 0; a < 2; ++a)
#pragma unroll
                for (int bn = 0; bn < 4; ++bn)
                    acc[a][bn] = __builtin_amdgcn_mfma_f32_16x16x32_bf16(af[a], bfr[bn], acc[a][bn], 0, 0, 0);
        }
        __syncthreads();
    }

#pragma unroll
    for (int a = 0; a < 2; ++a) {
        const size_t row = rowBase + wr * 32 + a * 16 + lg * 4;
#pragma unroll
        for (int bn = 0; bn < 4; ++bn) {
            const size_t col = colBase + wc * 64 + bn * 16 + lr;
#pragma unroll
            for (int r = 0; r < 4; ++r)
                C[(row + r) * 512 + col] = acc[a][bn][r] + bias[col];
        }
    }
}

// ---------------------------------------------------------------- flash attention v7 (R17-proven, FROZEN)
__global__ __launch_bounds__(256) void attn_kernel(
    const unsigned short* __restrict__ qb,
    const unsigned short* __restrict__ k_ln,
    const unsigned short* __restrict__ v_t,
    unsigned short* __restrict__ attn_out)
{
    extern __shared__ char smem[];
    const int blk = ((blockIdx.x & 7) << 7) | (blockIdx.x >> 3);   // bijective XCD swizzle (1024 % 8 == 0)
    const int qc = blk & 31, h = (blk >> 5) & 7, b = blk >> 8;
    const int t = threadIdx.x, w = t >> 6, lane = t & 63;
    const int lr = lane & 15, lg = lane >> 4;
    const int qrow0 = qc * 128 + w * 32;

    const unsigned short* qpA = qb + (size_t)(b * 4096 + qrow0 + lr) * 512 + h * 64 + lg * 8;
    const bf16x8 qa0 = *(const bf16x8*)(qpA);
    const bf16x8 qa1 = *(const bf16x8*)(qpA + 32);
    const bf16x8 qb0 = *(const bf16x8*)(qpA + 16 * 512);
    const bf16x8 qb1 = *(const bf16x8*)(qpA + 16 * 512 + 32);

    const char* kbase = (const char*)(k_ln + (size_t)b * 524288 + h * 64);
    const char* vbase = (const char*)(v_t + ((size_t)b * 512 + h * 64) * 1024);
    const int d0 = t * 16, d1 = 4096 + t * 16;
    const int r0 = d0 >> 7, cs0 = (d0 & 127) ^ ((r0 & 7) << 4);
    const int r1 = d1 >> 7, cs1 = (d1 & 127) ^ ((r1 & 7) << 4);
    const char* gK0 = kbase + r0 * 1024 + cs0;
    const char* gK1 = kbase + r1 * 1024 + cs1;
    const char* gV0 = vbase + r0 * 2048 + cs0;
    const char* gV1 = vbase + r1 * 2048 + cs1;

#define STAGE_KV(buf, kt) do { \
    gload_lds16(gK0 + (size_t)(kt) * 65536, smem + (buf) * 8192 + d0); \
    gload_lds16(gK1 + (size_t)(kt) * 65536, smem + (buf) * 8192 + d1); \
    gload_lds16(gV0 + (kt) * 128, smem + 16384 + (buf) * 8192 + d0); \
    gload_lds16(gV1 + (kt) * 128, smem + 16384 + (buf) * 8192 + d1); \
  } while (0)

    bf16x8 ones;
#pragma unroll
    for (int i = 0; i < 8; ++i) ones[i] = (short)0x3F80;   // bf16 1.0

    f32x4 accA[4] = {}, accB[4] = {};
    f32x4 psaccA = {}, psaccB = {};

    STAGE_KV(0, 0);
    __syncthreads();

    char* Pw = smem + 32768 + w * 2048;
    const int sw = (lr & 7) << 4;
    const int off0 = lr * 128 + ((lg * 16) ^ sw);
    const int off1 = lr * 128 + ((64 + lg * 16) ^ sw);
    int pwo[4];
#pragma unroll
    for (int tt = 0; tt < 4; ++tt) pwo[tt] = lr * 128 + ((tt * 32 + lg * 8) ^ sw);

#pragma unroll 2
    for (int kt = 0; kt < 16; ++kt) {
        const int cur = kt & 1;
        if (kt < 15) STAGE_KV(cur ^ 1, kt + 1);
        const char* KsB = smem + cur * 8192;
        const char* VsB = smem + 16384 + cur * 8192;

        // QK^T, operand-swapped: sa[tt][r] = S[key=tt*16+lg*4+r][q=lr] (pre-scaled via k_ln)
        f32x4 sa[4], sb[4];
#pragma unroll
        for (int tt = 0; tt < 4; ++tt) {
            const bf16x8 kf0 = *(const bf16x8*)(KsB + tt * 2048 + off0);
            const bf16x8 kf1 = *(const bf16x8*)(KsB + tt * 2048 + off1);
            f32x4 za = {}, zb = {};
            za = __builtin_amdgcn_mfma_f32_16x16x32_bf16(kf0, qa0, za, 0, 0, 0);
            za = __builtin_amdgcn_mfma_f32_16x16x32_bf16(kf1, qa1, za, 0, 0, 0);
            zb = __builtin_amdgcn_mfma_f32_16x16x32_bf16(kf0, qb0, zb, 0, 0, 0);
            zb = __builtin_amdgcn_mfma_f32_16x16x32_bf16(kf1, qb1, zb, 0, 0, 0);
            sa[tt] = za; sb[tt] = zb;
        }

        // half A: p = exp2(s), pack 4 consecutive keys, swizzled b64 write
#pragma unroll
        for (int tt = 0; tt < 4; ++tt) {
            float e0, e1, e2, e3;
            EXP2A(e0, sa[tt][0]); EXP2A(e1, sa[tt][1]);
            EXP2A(e2, sa[tt][2]); EXP2A(e3, sa[tt][3]);
            unsigned c0, c1;
            CVTPK(c0, e0, e1); CVTPK(c1, e2, e3);
            union { u32x2 u; s16x4 s; } pk; pk.u.x = c0; pk.u.y = c1;
            *(s16x4*)(Pw + pwo[tt]) = pk.s;
        }
        asm volatile("" ::: "memory");   // program-order the aliasing DS write->read
        const bf16x8 fa0 = *(const bf16x8*)(Pw + off0);
        const bf16x8 fa1 = *(const bf16x8*)(Pw + off1);
        asm volatile("" ::: "memory");

        // hoist V fragments to registers (same 8 ds_read_b128, issued once)
        bf16x8 vf0[4], vf1[4];
#pragma unroll
        for (int n2 = 0; n2 < 4; ++n2) {
            vf0[n2] = *(const bf16x8*)(VsB + n2 * 2048 + off0);
            vf1[n2] = *(const bf16x8*)(VsB + n2 * 2048 + off1);
        }

        // PV-A + psacc-A (MFMA pipe) — overlaps with half-B softmax (VALU pipe) below
#pragma unroll
        for (int n2 = 0; n2 < 4; ++n2) {
            accA[n2] = __builtin_amdgcn_mfma_f32_16x16x32_bf16(fa0, vf0[n2], accA[n2], 0, 0, 0);
            accA[n2] = __builtin_amdgcn_mfma_f32_16x16x32_bf16(fa1, vf1[n2], accA[n2], 0, 0, 0);
        }
        psaccA = __builtin_amdgcn_mfma_f32_16x16x32_bf16(fa0, ones, psaccA, 0, 0, 0);
        psaccA = __builtin_amdgcn_mfma_f32_16x16x32_bf16(fa1, ones, psaccA, 0, 0, 0);

        // half B reuses Pw (same-wave DS ops execute in order)
#pragma unroll
        for (int tt = 0; tt < 4; ++tt) {
            float e0, e1, e2, e3;
            EXP2A(e0, sb[tt][0]); EXP2A(e1, sb[tt][1]);
            EXP2A(e2, sb[tt][2]); EXP2A(e3, sb[tt][3]);
            unsigned c0, c1;
            CVTPK(c0, e0, e1); CVTPK(c1, e2, e3);
            union { u32x2 u; s16x4 s; } pk; pk.u.x = c0; pk.u.y = c1;
            *(s16x4*)(Pw + pwo[tt]) = pk.s;
        }
        asm volatile("" ::: "memory");
        const bf16x8 fb0 = *(const bf16x8*)(Pw + off0);
        const bf16x8 fb1 = *(const bf16x8*)(Pw + off1);

#pragma unroll
        for (int n2 = 0; n2 < 4; ++n2) {
            accB[n2] = __builtin_amdgcn_mfma_f32_16x16x32_bf16(fb0, vf0[n2], accB[n2], 0, 0, 0);
            accB[n2] = __builtin_amdgcn_mfma_f32_16x16x32_bf16(fb1, vf1[n2], accB[n2], 0, 0, 0);
        }
        psaccB = __builtin_amdgcn_mfma_f32_16x16x32_bf16(fb0, ones, psaccB, 0, 0, 0);
        psaccB = __builtin_amdgcn_mfma_f32_16x16x32_bf16(fb1, ones, psaccB, 0, 0, 0);
        __syncthreads();
    }
#undef STAGE_KV

    // psacc[r] = sum over all keys of P[q=lg*4+r][*] — matches output row indexing exactly
    float dA[4], dB[4];
#pragma unroll
    for (int r = 0; r < 4; ++r) {
        dA[r] = 1.0f / psaccA[r];
        dB[r] = 1.0f / psaccB[r];
    }
    unsigned short* oA = attn_out + (size_t)(b * 4096 + qrow0 + lg * 4) * 512 + h * 64;
#pragma unroll
    for (int n2 = 0; n2 < 4; ++n2)
#pragma unroll
        for (int r = 0; r < 4; ++r) {
            oA[(size_t)r * 512 + n2 * 16 + lr] = f2bf(accA[n2][r] * dA[r]);
            oA[(size_t)(16 + r) * 512 + n2 * 16 + lr] = f2bf(accB[n2][r] * dB[r]);
        }
}

// ---------------------------------------------------------------- launch
extern "C" void kernel_launch(void* const* d_in, const int* in_sizes, int n_in,
                              void* d_out, int out_size, void* d_ws, size_t ws_size,
                              hipStream_t stream)
{
    (void)in_sizes; (void)n_in; (void)out_size; (void)ws_size;
    const float* x       = (const float*)d_in[0];
    const float* w_qkv   = (const float*)d_in[1];
    const float* w_ke    = (const float*)d_in[2];
    const float* w_ve    = (const float*)d_in[3];
    const float* gamma_k = (const float*)d_in[4];
    const float* beta_k  = (const float*)d_in[5];
    const float* gamma_v = (const float*)d_in[6];
    const float* beta_v  = (const float*)d_in[7];
    const float* w_proj  = (const float*)d_in[8];
    const float* b_proj  = (const float*)d_in[9];
    float* out = (float*)d_out;

    char* ws = (char*)d_ws;
    unsigned short* qb     = (unsigned short*)(ws + 0);            // 16,777,216 (q-only projection)
    unsigned short* wtk    = (unsigned short*)(ws + 16777216);     // 2,097,152 (combined k weight)
    unsigned short* wtv    = (unsigned short*)(ws + 18874368);     // 2,097,152 (combined v weight)
    unsigned short* wqkvT  = (unsigned short*)(ws + 20971520);     // 1,048,576 (transposed k/v wqkv block)
    unsigned short* xb     = (unsigned short*)(ws + 50331648);     // 16,777,216 (reused: attn_out)
    unsigned short* attn_o = xb;
    float*          kredB  = (float*)(ws + 67108864);              // 16,777,216 (split-K partial ks=0)
    float*          kredA  = (float*)(ws + 83886080);              // 16,777,216 (split-K partial ks=1)
    unsigned short* k_ln   = (unsigned short*)(ws + 100663296);    // 4,194,304
    unsigned short* v_t    = (unsigned short*)(ws + 109051904);    // 4,194,304
    unsigned short* wqkvb  = (unsigned short*)(ws + 113246208);    // 1,572,864
    unsigned short* w2k    = (unsigned short*)(ws + 114819072);    // 2,097,152
    unsigned short* w2v    = (unsigned short*)(ws + 116916224);    // 2,097,152
    unsigned short* wprojb = (unsigned short*)(ws + 119013376);    // 524,288

    prep_kernel<<<11776, 256, 0, stream>>>(x, w_qkv, w_proj, w_ke, w_ve,
                                           xb, wqkvb, wprojb, w2k, w2v, wqkvT);

    // combined weights: Wt[o][p*512+d] = sum_c w2[o][p,c] * w_qkv[512+sel*512+c][d]
    gemm_wt<<<dim3(4, 4, 8), 256, 0, stream>>>(w2k, w2v, wqkvT, wtk, wtv);

    // fused: q = x @ w_qkv[0:512]^T  AND  k/v reduction split-K=2 (partials kredB/kredA)
    gemm_qred<<<dim3(4, 256), 256, 0, stream>>>(xb, wqkvb, qb, wtk, wtv, kredB);

    // merged: k-LN (blocks 0..4095) + v-LN+transpose (blocks 4096..4607)
    ln_all<<<4608, 256, 0, stream>>>(kredA, kredB, gamma_k, beta_k, gamma_v, beta_v,
                                     k_ln, v_t);

    attn_kernel<<<1024, 256, 40960, stream>>>(qb, k_ln, v_t, attn_o);

    // out = attn_o @ w_proj^T + b_proj   [16384 x 512], K=512, f32 out, 64x128 tiles
    gemm_proj<<<dim3(4, 256), 256, 0, stream>>>(attn_o, wprojb, out, b_proj);
}